// Round 1
// baseline (95.622 us; speedup 1.0000x reference)
//
#include <hip/hip_runtime.h>
#include <hip/hip_bf16.h>
#include <cstdint>
#include <cstddef>

#define DIMC 1024
#define HEADS 16
#define HD 64
#define WINDOW 128
#define BB 2
#define TT 2048
#define NTOK (BB*TT)       // 4096
#define QKVN (3*DIMC)      // 3072

typedef __bf16 bf16;
typedef __bf16 bf16x8 __attribute__((ext_vector_type(8)));
typedef __bf16 bf16x4 __attribute__((ext_vector_type(4)));
typedef float f32x4 __attribute__((ext_vector_type(4)));
typedef unsigned int u32;

typedef const __attribute__((address_space(1))) u32* gp1_t;
typedef __attribute__((address_space(3))) u32* lp3_t;

__device__ __forceinline__ void gload16(const void* g, void* l) {
  // async global->LDS, 16B per lane; LDS dest = uniform base + lane*16
  __builtin_amdgcn_global_load_lds((gp1_t)g, (lp3_t)l, 16, 0, 0);
}

// ---------------------------------------------------------------- cast kernel
__global__ void cast3_kernel(const float* __restrict__ x,
                             const float* __restrict__ wq,
                             const float* __restrict__ wp,
                             bf16* __restrict__ xo,
                             bf16* __restrict__ wqo,
                             bf16* __restrict__ wpo) {
  const int NX = NTOK * DIMC / 4;        // 1048576 float4s
  const int NQ = QKVN * DIMC / 4;        // 786432
  const int NP = DIMC * DIMC / 4;        // 262144
  const int total = NX + NQ + NP;
  typedef float float4v __attribute__((ext_vector_type(4)));
  for (int i = blockIdx.x * blockDim.x + threadIdx.x; i < total;
       i += gridDim.x * blockDim.x) {
    const float4v* src; bf16* dst; int j;
    if (i < NX)            { src = (const float4v*)x;  dst = xo;  j = i; }
    else if (i < NX + NQ)  { src = (const float4v*)wq; dst = wqo; j = i - NX; }
    else                   { src = (const float4v*)wp; dst = wpo; j = i - NX - NQ; }
    float4v v = src[j];
    bf16x4 o;
    o[0] = (bf16)v[0]; o[1] = (bf16)v[1]; o[2] = (bf16)v[2]; o[3] = (bf16)v[3];
    ((bf16x4*)dst)[j] = o;
  }
}

// ---------------------------------------------------------------- GEMM (C = A * B^T)
// A: [M][1024] bf16 row-major, Bw: [N_][1024] bf16 row-major (the "weight" layout),
// C[row][col] = sum_k A[row][k]*Bw[col][k].  128x128 tile, BK=32, 4 waves (2x2),
// 16x16x32 bf16 MFMA, global_load_lds width-16, double-buffered LDS.
template<int N_, bool BF16OUT>
__global__ __launch_bounds__(256, 2) void gemm_bt_kernel(
    const bf16* __restrict__ A, const bf16* __restrict__ Bw,
    bf16* __restrict__ Cb, float* __restrict__ Cf,
    const float* __restrict__ bias) {
  constexpr int K = 1024;
  constexpr int KB = K * 2;              // row stride in bytes
  __shared__ bf16 As[2][128 * 32];
  __shared__ bf16 Bs[2][128 * 32];

  const int tid = threadIdx.x;
  const int w = tid >> 6, l = tid & 63;
  const int bm = blockIdx.x & 31;        // NTOK/128 == 32
  const int bn = blockIdx.x >> 5;
  const int wm = w >> 1, wn = w & 1;
  const int lr = l & 15, lg = l >> 4;

  // staging: per wave 2 issues for A (rows w*32..w*32+31), 2 for B
  const int srow = w * 32 + (l >> 2);
  const int scolb = (l & 3) * 16;
  const char* Agb = (const char*)A + (size_t)(bm * 128 + srow) * KB + scolb;
  const char* Bgb = (const char*)Bw + (size_t)(bn * 128 + srow) * KB + scolb;

  f32x4 acc[4][4] = {};

  auto stage = [&](int buf, int t) {
    const char* ag = Agb + t * 64;
    const char* bg = Bgb + t * 64;
    gload16(ag,            &As[buf][(w * 32) * 32]);
    gload16(ag + 16 * KB,  &As[buf][(w * 32 + 16) * 32]);
    gload16(bg,            &Bs[buf][(w * 32) * 32]);
    gload16(bg + 16 * KB,  &Bs[buf][(w * 32 + 16) * 32]);
  };

  stage(0, 0);
  __syncthreads();
  constexpr int NTiles = K / 32;
  int buf = 0;
  for (int t = 0; t < NTiles; ++t) {
    if (t + 1 < NTiles) stage(buf ^ 1, t + 1);
    bf16x8 af[4], bfr[4];
#pragma unroll
    for (int m = 0; m < 4; m++)
      af[m] = *(const bf16x8*)&As[buf][(wm * 64 + m * 16 + lr) * 32 + lg * 8];
#pragma unroll
    for (int n = 0; n < 4; n++)
      bfr[n] = *(const bf16x8*)&Bs[buf][(wn * 64 + n * 16 + lr) * 32 + lg * 8];
#pragma unroll
    for (int m = 0; m < 4; m++)
#pragma unroll
      for (int n = 0; n < 4; n++)
        acc[m][n] = __builtin_amdgcn_mfma_f32_16x16x32_bf16(af[m], bfr[n], acc[m][n], 0, 0, 0);
    __syncthreads();
    buf ^= 1;
  }

  // epilogue: C row = (lane>>4)*4 + j, col = lane&15 within each 16x16 frag
#pragma unroll
  for (int m = 0; m < 4; m++) {
    const int row = bm * 128 + wm * 64 + m * 16 + lg * 4;
#pragma unroll
    for (int n = 0; n < 4; n++) {
      const int col = bn * 128 + wn * 64 + n * 16 + lr;
#pragma unroll
      for (int j = 0; j < 4; j++) {
        if constexpr (BF16OUT) {
          Cb[(size_t)(row + j) * N_ + col] = (bf16)acc[m][n][j];
        } else {
          Cf[(size_t)(row + j) * N_ + col] = acc[m][n][j] + bias[col];
        }
      }
    }
  }
}

// ---------------------------------------------------------------- attention
// qkv: [NTOK][3072] bf16 (q|k|v each 1024 = 16 heads * 64).
// One WG per (b, h, 64-query block). 4 waves x 16 q rows. KV blocks of 64,
// window |i-j|<=128 -> blocks qb-2..qb+2.  Online softmax in fp32.
__global__ __launch_bounds__(256, 2) void attn_kernel(const bf16* __restrict__ qkv,
                                                      bf16* __restrict__ out) {
  __shared__ bf16 Kl[64][72];     // K tile, +8 pad
  __shared__ bf16 Vt[64][72];     // V^T tile: Vt[d][kv]
  __shared__ bf16 Pl[4][16][72];  // per-wave P staging

  const int tid = threadIdx.x, w = tid >> 6, l = tid & 63;
  const int qb = blockIdx.x & 31, bh = blockIdx.x >> 5;
  const int b = bh >> 4, h = bh & 15;
  const int q0 = qb * 64;
  const int lr = l & 15, lg = l >> 4;
  const float SC = 0.18033688011f;   // 0.125 * log2(e)

  // Q fragments (hoisted): row = q0 + w*16 + lr, k = kf*32 + lg*8 .. +8
  bf16x8 qf[2];
  {
    const bf16* qp = qkv + (size_t)(b * TT + q0 + w * 16 + lr) * QKVN + h * HD + lg * 8;
    qf[0] = *(const bf16x8*)qp;
    qf[1] = *(const bf16x8*)(qp + 32);
  }

  f32x4 Oa[4] = {};
  float mrow[4], lrow[4];
#pragma unroll
  for (int j = 0; j < 4; j++) { mrow[j] = -1e30f; lrow[j] = 0.f; }

  int kb0 = qb - 2; if (kb0 < 0) kb0 = 0;
  int kb1 = qb + 2; if (kb1 > 31) kb1 = 31;

  for (int kb = kb0; kb <= kb1; ++kb) {
    const int kvbase = kb * 64;
    // ---- stage K (row-major, padded) : 512 16B tasks over 256 threads
#pragma unroll
    for (int task = 0; task < 2; task++) {
      int lin = tid + 256 * task;
      int r = lin >> 3, cb = lin & 7;
      const bf16* kp = qkv + (size_t)(b * TT + kvbase + r) * QKVN + DIMC + h * HD + cb * 8;
      *(bf16x8*)&Kl[r][cb * 8] = *(const bf16x8*)kp;
    }
    // ---- stage V transposed: lane-per-row so LDS writes are conflict-free
#pragma unroll
    for (int task = 0; task < 2; task++) {
      int lin = tid + 256 * task;
      int r = lin & 63, c0 = (lin >> 6) * 8;
      bf16x8 vv = *(const bf16x8*)(qkv + (size_t)(b * TT + kvbase + r) * QKVN + 2 * DIMC + h * HD + c0);
#pragma unroll
      for (int e = 0; e < 8; e++) Vt[c0 + e][r] = vv[e];
    }
    __syncthreads();

    // ---- S = Q K^T  (4 frags of 16x16 over kv 0..63)
    f32x4 Sa[4] = {};
#pragma unroll
    for (int kf = 0; kf < 2; kf++)
#pragma unroll
      for (int nf = 0; nf < 4; nf++) {
        bf16x8 kfr = *(const bf16x8*)&Kl[nf * 16 + lr][kf * 32 + lg * 8];
        Sa[nf] = __builtin_amdgcn_mfma_f32_16x16x32_bf16(qf[kf], kfr, Sa[nf], 0, 0, 0);
      }

    // ---- mask + scale (log2 domain), block row-max
    float mblk[4];
#pragma unroll
    for (int j = 0; j < 4; j++) mblk[j] = -1e30f;
    const int qrow_ = q0 + w * 16 + lg * 4;
#pragma unroll
    for (int nf = 0; nf < 4; nf++) {
      int kv = kvbase + nf * 16 + lr;
#pragma unroll
      for (int j = 0; j < 4; j++) {
        int dq = qrow_ + j - kv;
        float s = Sa[nf][j] * SC;
        if (dq > WINDOW || dq < -WINDOW) s = -1e30f;
        Sa[nf][j] = s;
        mblk[j] = fmaxf(mblk[j], s);
      }
    }
#pragma unroll
    for (int j = 0; j < 4; j++) {
#pragma unroll
      for (int sh = 1; sh < 16; sh <<= 1)
        mblk[j] = fmaxf(mblk[j], __shfl_xor(mblk[j], sh, 16));
    }
    // ---- online softmax update
    float scl[4];
#pragma unroll
    for (int j = 0; j < 4; j++) {
      float mn = fmaxf(mrow[j], mblk[j]);
      scl[j] = exp2f(mrow[j] - mn);
      mrow[j] = mn;
    }
    float rsum[4] = {0.f, 0.f, 0.f, 0.f};
#pragma unroll
    for (int nf = 0; nf < 4; nf++)
#pragma unroll
      for (int j = 0; j < 4; j++) {
        float p = exp2f(Sa[nf][j] - mrow[j]);
        Sa[nf][j] = p;
        rsum[j] += p;
      }
#pragma unroll
    for (int j = 0; j < 4; j++) {
#pragma unroll
      for (int sh = 1; sh < 16; sh <<= 1)
        rsum[j] += __shfl_xor(rsum[j], sh, 16);
      lrow[j] = lrow[j] * scl[j] + rsum[j];
    }
#pragma unroll
    for (int nf = 0; nf < 4; nf++)
#pragma unroll
      for (int j = 0; j < 4; j++) Oa[nf][j] *= scl[j];

    // ---- P (acc layout) -> LDS -> A-frag layout, then O += P V
#pragma unroll
    for (int nf = 0; nf < 4; nf++)
#pragma unroll
      for (int j = 0; j < 4; j++)
        Pl[w][lg * 4 + j][nf * 16 + lr] = (bf16)Sa[nf][j];
#pragma unroll
    for (int kf = 0; kf < 2; kf++) {
      bf16x8 pf = *(const bf16x8*)&Pl[w][lr][kf * 32 + lg * 8];
#pragma unroll
      for (int nf = 0; nf < 4; nf++) {
        bf16x8 vfr = *(const bf16x8*)&Vt[nf * 16 + lr][kf * 32 + lg * 8];
        Oa[nf] = __builtin_amdgcn_mfma_f32_16x16x32_bf16(pf, vfr, Oa[nf], 0, 0, 0);
      }
    }
    __syncthreads();
  }

  // ---- epilogue: out[b*T + q][h*64 + d] = O / l
#pragma unroll
  for (int nf = 0; nf < 4; nf++) {
#pragma unroll
    for (int j = 0; j < 4; j++) {
      int qrow = q0 + w * 16 + lg * 4 + j;
      int d = nf * 16 + lr;
      out[(size_t)(b * TT + qrow) * DIMC + h * HD + d] = (bf16)(Oa[nf][j] / lrow[j]);
    }
  }
}

// ---------------------------------------------------------------- launch
extern "C" void kernel_launch(void* const* d_in, const int* in_sizes, int n_in,
                              void* d_out, int out_size, void* d_ws, size_t ws_size,
                              hipStream_t stream) {
  const float* x     = (const float*)d_in[0];
  const float* Wqkv  = (const float*)d_in[1];
  const float* Wproj = (const float*)d_in[2];
  const float* bproj = (const float*)d_in[3];
  float* out = (float*)d_out;

  char* ws = (char*)d_ws;
  bf16* xb   = (bf16*)(ws);                       // 4194304 elems = 8388608 B
  bf16* wqb  = (bf16*)(ws + 8388608);             // 3145728 elems = 6291456 B
  bf16* wpb  = (bf16*)(ws + 14680064);            // 1048576 elems = 2097152 B
  bf16* qkvb = (bf16*)(ws + 16777216);            // 12582912 elems = 25165824 B
  bf16* aob  = (bf16*)(ws + 41943040);            // 4194304 elems = 8388608 B
  // total ws use: 50331648 B

  cast3_kernel<<<2048, 256, 0, stream>>>(x, Wqkv, Wproj, xb, wqb, wpb);
  gemm_bt_kernel<QKVN, true><<<dim3(32 * 24), 256, 0, stream>>>(xb, wqb, qkvb, nullptr, nullptr);
  attn_kernel<<<1024, 256, 0, stream>>>(qkvb, aob);
  gemm_bt_kernel<DIMC, false><<<dim3(32 * 8), 256, 0, stream>>>(aob, wpb, nullptr, out, bproj);
}